// Round 1
// baseline (57.269 us; speedup 1.0000x reference)
//
#include <hip/hip_runtime.h>

// BilinearSampler: B=128, H=256, W=256, C=3
// Input row layout: [theta(6) | image(H*W*C)] per batch, f32.
// Output: (B, H, W, C) f32.

constexpr int BB = 128;
constexpr int HH = 256;
constexpr int WW = 256;
constexpr int CC = 3;
constexpr int IMG_ELEMS = HH * WW * CC;          // 196608
constexpr int ROW_ELEMS = 6 + IMG_ELEMS;         // 196614

struct f3 { float x, y, z; };

__global__ __launch_bounds__(256) void bilinear_sampler_kernel(
    const float* __restrict__ in, float* __restrict__ out)
{
    // One thread per output pixel; block(256) = one output row of one batch.
    const int w = threadIdx.x;            // 0..255
    const int h = blockIdx.x & (HH - 1);  // 0..255
    const int b = blockIdx.x >> 8;        // 0..127

    const float* __restrict__ base = in + (long long)b * ROW_ELEMS;
    // Wave-uniform theta loads (same address across block -> broadcast).
    const float t00 = base[0], t01 = base[1], t02 = base[2];
    const float t10 = base[3], t11 = base[4], t12 = base[5];
    const float* __restrict__ img = base + 6;

    // linspace(-1,1,N): -1 + (2/(N-1))*i
    const float xt = -1.0f + (2.0f / (WW - 1)) * (float)w;
    const float yt = -1.0f + (2.0f / (HH - 1)) * (float)h;

    const float x_s = t00 * xt + t01 * yt + t02;
    const float y_s = t10 * xt + t11 * yt + t12;

    const float x = 0.5f * (x_s + 1.0f) * (float)(WW - 1);
    const float y = 0.5f * (y_s + 1.0f) * (float)(HH - 1);

    int x0 = (int)floorf(x);
    int x1 = x0 + 1;
    int y0 = (int)floorf(y);
    int y1 = y0 + 1;

    // Clip FIRST, then derive the float corners used in the weights
    // (matches the reference, which clips before x0f/x1f/y0f/y1f).
    x0 = min(max(x0, 0), WW - 1);
    x1 = min(max(x1, 0), WW - 1);
    y0 = min(max(y0, 0), HH - 1);
    y1 = min(max(y1, 0), HH - 1);

    const float x0f = (float)x0, x1f = (float)x1;
    const float y0f = (float)y0, y1f = (float)y1;

    const float wa = (x1f - x) * (y1f - y);
    const float wb = (x1f - x) * (y - y0f);
    const float wc = (x - x0f) * (y1f - y);
    const float wd = (x - x0f) * (y - y0f);

    const f3 Ia = *reinterpret_cast<const f3*>(img + (y0 * WW + x0) * CC);
    const f3 Ib = *reinterpret_cast<const f3*>(img + (y1 * WW + x0) * CC);
    const f3 Ic = *reinterpret_cast<const f3*>(img + (y0 * WW + x1) * CC);
    const f3 Id = *reinterpret_cast<const f3*>(img + (y1 * WW + x1) * CC);

    f3 o;
    o.x = wa * Ia.x + wb * Ib.x + wc * Ic.x + wd * Id.x;
    o.y = wa * Ia.y + wb * Ib.y + wc * Ic.y + wd * Id.y;
    o.z = wa * Ia.z + wb * Ib.z + wc * Ic.z + wd * Id.z;

    const long long oidx = ((long long)blockIdx.x * WW + w) * CC;
    *reinterpret_cast<f3*>(out + oidx) = o;
}

extern "C" void kernel_launch(void* const* d_in, const int* in_sizes, int n_in,
                              void* d_out, int out_size, void* d_ws, size_t ws_size,
                              hipStream_t stream)
{
    const float* in = (const float*)d_in[0];
    float* out = (float*)d_out;
    // grid = B*H blocks (one output row each), block = W threads.
    dim3 grid(BB * HH), block(WW);
    bilinear_sampler_kernel<<<grid, block, 0, stream>>>(in, out);
}

// Round 2
// 54.376 us; speedup vs baseline: 1.0532x; 1.0532x over previous
//
#include <hip/hip_runtime.h>

// BilinearSampler: B=128, H=256, W=256, C=3
// Input row layout: [theta(6) | image(H*W*C)] per batch, f32.
// Output: (B, H, W, C) f32.
//
// Key idea: the two x-neighbor pixels (x0c, x1c) are always either adjacent
// (normal case) or identical (clipped case). So one 6-float contiguous load
// at xp = clamp(x0, 0, W-2) plus a per-lane select covers both, halving the
// number of scattered gather instructions (2 per pixel instead of 4).
// Each thread computes 2 adjacent pixels for 2x memory-level parallelism.

constexpr int BB = 128;
constexpr int HH = 256;
constexpr int WW = 256;
constexpr int CC = 3;
constexpr long long IMG_ELEMS = (long long)HH * WW * CC;   // 196608
constexpr long long ROW_ELEMS = 6 + IMG_ELEMS;             // 196614

struct F6 { float v[6]; };                       // align 4: gather loads are only 4B-aligned
struct __attribute__((aligned(8))) F6s { float v[6]; };  // stores are 8B-aligned

__global__ __launch_bounds__(256) void bilinear_sampler_kernel(
    const float* __restrict__ in, float* __restrict__ out)
{
    const int tid = threadIdx.x;
    const int u   = tid & 127;            // pixel-pair index: covers w = 2u, 2u+1
    const int rr  = tid >> 7;             // row within block (0/1)
    const int b   = blockIdx.x >> 7;      // batch
    const int h   = 2 * (blockIdx.x & (HH/2 - 1)) + rr;

    const float* __restrict__ base = in + (long long)b * ROW_ELEMS;
    // Block-uniform theta loads -> scalar broadcasts.
    const float t00 = base[0], t01 = base[1], t02 = base[2];
    const float t10 = base[3], t11 = base[4], t12 = base[5];
    const float* __restrict__ img = base + 6;

    const float yt = -1.0f + (2.0f / (HH - 1)) * (float)h;

    float o[6];

    #pragma unroll
    for (int p = 0; p < 2; ++p) {
        const int w = 2 * u + p;
        const float xt = -1.0f + (2.0f / (WW - 1)) * (float)w;

        // Same expression shape as the passing round-1 kernel.
        const float x_s = t00 * xt + t01 * yt + t02;
        const float y_s = t10 * xt + t11 * yt + t12;
        const float x = 0.5f * (x_s + 1.0f) * (float)(WW - 1);
        const float y = 0.5f * (y_s + 1.0f) * (float)(HH - 1);

        const int x0 = (int)floorf(x);
        const int y0 = (int)floorf(y);

        const int x0c = min(max(x0,     0), WW - 1);
        const int x1c = min(max(x0 + 1, 0), WW - 1);
        const int y0c = min(max(y0,     0), HH - 1);
        const int y1c = min(max(y0 + 1, 0), HH - 1);

        // Pair-load base column: pixels (xp, xp+1) cover {x0c, x1c} always.
        const int xp = min(max(x0, 0), WW - 2);

        const F6 lo = *reinterpret_cast<const F6*>(img + ((long long)y0c * WW + xp) * CC);
        const F6 hi = *reinterpret_cast<const F6*>(img + ((long long)y1c * WW + xp) * CC);

        // Which of the two loaded pixels is x0c / x1c:
        //   x0 in [0, W-2] -> (P0, P1); x0 >= W-1 -> (P1, P1); x0 < 0 -> (P0, P0).
        const bool selA = (x0 > WW - 2);  // Ia/Ib = P1 only on right clip
        const bool selC = (x0 >= 0);      // Ic/Id = P1 except on left clip

        const float x0f = (float)x0c, x1f = (float)x1c;
        const float y0f = (float)y0c, y1f = (float)y1c;
        const float wa = (x1f - x) * (y1f - y);
        const float wb = (x1f - x) * (y - y0f);
        const float wc = (x - x0f) * (y1f - y);
        const float wd = (x - x0f) * (y - y0f);

        #pragma unroll
        for (int c = 0; c < 3; ++c) {
            const float Ia = selA ? lo.v[3 + c] : lo.v[c];
            const float Ib = selA ? hi.v[3 + c] : hi.v[c];
            const float Ic = selC ? lo.v[3 + c] : lo.v[c];
            const float Id = selC ? hi.v[3 + c] : hi.v[c];
            o[3 * p + c] = wa * Ia + wb * Ib + wc * Ic + wd * Id;
        }
    }

    const long long grow = 2LL * blockIdx.x + rr;          // global output row
    float* op = out + (grow * WW + 2 * u) * CC;            // 24B-aligned
    F6s st;
    #pragma unroll
    for (int i = 0; i < 6; ++i) st.v[i] = o[i];
    *reinterpret_cast<F6s*>(op) = st;
}

extern "C" void kernel_launch(void* const* d_in, const int* in_sizes, int n_in,
                              void* d_out, int out_size, void* d_ws, size_t ws_size,
                              hipStream_t stream)
{
    const float* in = (const float*)d_in[0];
    float* out = (float*)d_out;
    // grid: one block covers 2 output rows (256 threads x 2 pixels).
    dim3 grid(BB * HH / 2), block(256);
    bilinear_sampler_kernel<<<grid, block, 0, stream>>>(in, out);
}

// Round 3
// 52.588 us; speedup vs baseline: 1.0890x; 1.0340x over previous
//
#include <hip/hip_runtime.h>

// BilinearSampler: B=128, H=256, W=256, C=3
// Input row layout: [theta(6) | image(H*W*C)] per batch, f32.
// Output: (B, H, W, C) f32.
//
// Round 3 changes (all memory-path):
//  1. Explicit dwordx4+dwordx2 gather loads (the round-2 F6 struct was only
//     4B-aligned and may have been legalized to 6x global_load_dword,
//     leaving the VMEM op count identical to round 1 -- explaining the null).
//  2. Nontemporal output stores: keep the 98MB output stream from evicting
//     the gather-reuse lines out of the 4MB per-XCD L2.
//  3. XCD-chunked bijective block swizzle (16384 % 8 == 0): each batch image
//     is fetched/cached by one XCD's L2 instead of all eight.

constexpr int BB = 128;
constexpr int HH = 256;
constexpr int WW = 256;
constexpr int CC = 3;
constexpr long long IMG_ELEMS = (long long)HH * WW * CC;   // 196608
constexpr long long ROW_ELEMS = 6 + IMG_ELEMS;             // 196614
constexpr int NWG = BB * HH / 2;                           // 16384 blocks

typedef float f32x4 __attribute__((ext_vector_type(4)));
typedef f32x4 f32x4_a4 __attribute__((aligned(4)));
typedef float f32x2 __attribute__((ext_vector_type(2)));
typedef f32x2 f32x2_a4 __attribute__((aligned(4)));

__global__ __launch_bounds__(256) void bilinear_sampler_kernel(
    const float* __restrict__ in, float* __restrict__ out)
{
    // XCD-chunked swizzle: blocks with the same (bid & 7) land on the same
    // XCD (round-robin dispatch); give each XCD a contiguous chunk of the
    // batch*row space so one image's gather lines live in one L2.
    const int bid = blockIdx.x;
    const int swz = (bid & 7) * (NWG >> 3) + (bid >> 3);

    const int tid = threadIdx.x;
    const int u   = tid & 127;            // pixel-pair index: w = 2u, 2u+1
    const int rr  = tid >> 7;             // row within block (0/1)
    const int b   = swz >> 7;             // batch
    const int h   = 2 * (swz & 127) + rr;

    const float* __restrict__ base = in + (long long)b * ROW_ELEMS;
    const float t00 = base[0], t01 = base[1], t02 = base[2];
    const float t10 = base[3], t11 = base[4], t12 = base[5];
    const float* __restrict__ img = base + 6;

    const float yt = -1.0f + (2.0f / (HH - 1)) * (float)h;

    float o[6];

    #pragma unroll
    for (int p = 0; p < 2; ++p) {
        const int w = 2 * u + p;
        const float xt = -1.0f + (2.0f / (WW - 1)) * (float)w;

        const float x_s = t00 * xt + t01 * yt + t02;
        const float y_s = t10 * xt + t11 * yt + t12;
        const float x = 0.5f * (x_s + 1.0f) * (float)(WW - 1);
        const float y = 0.5f * (y_s + 1.0f) * (float)(HH - 1);

        const int x0 = (int)floorf(x);
        const int y0 = (int)floorf(y);

        const int x0c = min(max(x0,     0), WW - 1);
        const int x1c = min(max(x0 + 1, 0), WW - 1);
        const int y0c = min(max(y0,     0), HH - 1);
        const int y1c = min(max(y0 + 1, 0), HH - 1);
        const int xp  = min(max(x0, 0), WW - 2);   // pair-load base column

        // Two x-neighbors are adjacent (or identical when clipped): one
        // 6-float contiguous load per row, as dwordx4 + dwordx2.
        const float* plo = img + (y0c * WW + xp) * CC;
        const float* phi = img + (y1c * WW + xp) * CC;
        const f32x4_a4 lo4 = *reinterpret_cast<const f32x4_a4*>(plo);
        const f32x2_a4 lo2 = *reinterpret_cast<const f32x2_a4*>(plo + 4);
        const f32x4_a4 hi4 = *reinterpret_cast<const f32x4_a4*>(phi);
        const f32x2_a4 hi2 = *reinterpret_cast<const f32x2_a4*>(phi + 4);

        // P0 = pixel xp, P1 = pixel xp+1 (static indices only -> cndmask).
        const float loP0[3] = {lo4.x, lo4.y, lo4.z};
        const float loP1[3] = {lo4.w, lo2.x, lo2.y};
        const float hiP0[3] = {hi4.x, hi4.y, hi4.z};
        const float hiP1[3] = {hi4.w, hi2.x, hi2.y};

        //   x0 in [0, W-2] -> (P0, P1); x0 >= W-1 -> (P1, P1); x0 < 0 -> (P0, P0).
        const bool selA = (x0 > WW - 2);  // Ia/Ib = P1 only on right clip
        const bool selC = (x0 >= 0);      // Ic/Id = P1 except on left clip

        const float x0f = (float)x0c, x1f = (float)x1c;
        const float y0f = (float)y0c, y1f = (float)y1c;
        const float wa = (x1f - x) * (y1f - y);
        const float wb = (x1f - x) * (y - y0f);
        const float wc = (x - x0f) * (y1f - y);
        const float wd = (x - x0f) * (y - y0f);

        #pragma unroll
        for (int c = 0; c < 3; ++c) {
            const float Ia = selA ? loP1[c] : loP0[c];
            const float Ib = selA ? hiP1[c] : hiP0[c];
            const float Ic = selC ? loP1[c] : loP0[c];
            const float Id = selC ? hiP1[c] : hiP0[c];
            o[3 * p + c] = wa * Ia + wb * Ib + wc * Ic + wd * Id;
        }
    }

    const long long grow = 2LL * swz + rr;           // global output row
    float* op = out + (grow * WW + 2 * u) * CC;      // 8B-aligned
    const f32x4 s0 = {o[0], o[1], o[2], o[3]};
    const f32x2 s1 = {o[4], o[5]};
    __builtin_nontemporal_store(s0, reinterpret_cast<f32x4_a4*>(op));
    __builtin_nontemporal_store(s1, reinterpret_cast<f32x2_a4*>(op + 4));
}

extern "C" void kernel_launch(void* const* d_in, const int* in_sizes, int n_in,
                              void* d_out, int out_size, void* d_ws, size_t ws_size,
                              hipStream_t stream)
{
    const float* in = (const float*)d_in[0];
    float* out = (float*)d_out;
    dim3 grid(NWG), block(256);
    bilinear_sampler_kernel<<<grid, block, 0, stream>>>(in, out);
}

// Round 4
// 41.481 us; speedup vs baseline: 1.3806x; 1.2678x over previous
//
#include <hip/hip_runtime.h>

// BilinearSampler: B=128, H=256, W=256, C=3
// Input row layout: [theta(6) | image(H*W*C)] per batch, f32.
//
// Model (fits r1-r3, all ~70us): cost ~= distinct-cache-line requests from
// gathers, ~1/cycle/CU. Sample points step (t00,t10) px per output-w step and
// (t01,t11) per output-h step. Lanes along w touch a new image row per lane
// when |t10|~1 -> ~64 lines per gather instruction.
//
// Round 4: per-batch adaptive lane direction. Walk lanes along whichever
// output dim has the smaller image-row step (|t10| vs |t11|), 1 px per lane,
// so lanes share image rows/lines within each gather instruction. Case B
// (lanes along h) stores via an LDS transpose to keep stores coalesced.
// Per-pixel sampling arithmetic is identical to the passing round-3 kernel.

constexpr int BB = 128;
constexpr int HH = 256;
constexpr int WW = 256;
constexpr int CC = 3;
constexpr long long IMG_ELEMS = (long long)HH * WW * CC;   // 196608
constexpr long long ROW_ELEMS = 6 + IMG_ELEMS;             // 196614
constexpr int NWG = BB * 32;                               // 4096 blocks, %8==0
constexpr int LDSW = 98;  // case-B LDS row pitch in dwords (96 data + 2 pad):
                          // even -> 8B-aligned b64 reads; 98%32=2 -> ~free banks

typedef float f32x4 __attribute__((ext_vector_type(4)));
typedef float f32x2 __attribute__((ext_vector_type(2)));
typedef f32x4 f32x4_a4 __attribute__((aligned(4)));
typedef f32x2 f32x2_a4 __attribute__((aligned(4)));
struct F3 { float v[3]; };

__device__ __forceinline__ void sample_px(
    const float* __restrict__ img,
    float t00, float t01, float t02, float t10, float t11, float t12,
    int w, int h, float o[3])
{
    const float xt = -1.0f + (2.0f / (WW - 1)) * (float)w;
    const float yt = -1.0f + (2.0f / (HH - 1)) * (float)h;
    const float x_s = t00 * xt + t01 * yt + t02;
    const float y_s = t10 * xt + t11 * yt + t12;
    const float x = 0.5f * (x_s + 1.0f) * (float)(WW - 1);
    const float y = 0.5f * (y_s + 1.0f) * (float)(HH - 1);

    const int x0 = (int)floorf(x);
    const int y0 = (int)floorf(y);
    const int x0c = min(max(x0,     0), WW - 1);
    const int x1c = min(max(x0 + 1, 0), WW - 1);
    const int y0c = min(max(y0,     0), HH - 1);
    const int y1c = min(max(y0 + 1, 0), HH - 1);
    const int xp  = min(max(x0, 0), WW - 2);   // pair-load base column

    const float* plo = img + (y0c * WW + xp) * CC;
    const float* phi = img + (y1c * WW + xp) * CC;
    const f32x4_a4 lo4 = *reinterpret_cast<const f32x4_a4*>(plo);
    const f32x2_a4 lo2 = *reinterpret_cast<const f32x2_a4*>(plo + 4);
    const f32x4_a4 hi4 = *reinterpret_cast<const f32x4_a4*>(phi);
    const f32x2_a4 hi2 = *reinterpret_cast<const f32x2_a4*>(phi + 4);

    const float loP0[3] = {lo4.x, lo4.y, lo4.z};
    const float loP1[3] = {lo4.w, lo2.x, lo2.y};
    const float hiP0[3] = {hi4.x, hi4.y, hi4.z};
    const float hiP1[3] = {hi4.w, hi2.x, hi2.y};

    const bool selA = (x0 > WW - 2);  // Ia/Ib = P1 only on right clip
    const bool selC = (x0 >= 0);      // Ic/Id = P1 except on left clip

    const float x0f = (float)x0c, x1f = (float)x1c;
    const float y0f = (float)y0c, y1f = (float)y1c;
    const float wa = (x1f - x) * (y1f - y);
    const float wb = (x1f - x) * (y - y0f);
    const float wc = (x - x0f) * (y1f - y);
    const float wd = (x - x0f) * (y - y0f);

    #pragma unroll
    for (int c = 0; c < 3; ++c) {
        const float Ia = selA ? loP1[c] : loP0[c];
        const float Ib = selA ? hiP1[c] : hiP0[c];
        const float Ic = selC ? loP1[c] : loP0[c];
        const float Id = selC ? hiP1[c] : hiP0[c];
        o[c] = wa * Ia + wb * Ib + wc * Ic + wd * Id;
    }
}

__global__ __launch_bounds__(256) void bilinear_sampler_kernel(
    const float* __restrict__ in, float* __restrict__ out)
{
    __shared__ float lds[64 * LDSW];

    // XCD-chunked bijective swizzle (4096 % 8 == 0).
    const int bid = blockIdx.x;
    const int swz = (bid & 7) * (NWG >> 3) + (bid >> 3);
    const int b    = swz >> 5;        // batch
    const int beta = swz & 31;        // block-within-batch

    const float* __restrict__ base = in + (long long)b * ROW_ELEMS;
    const float t00 = base[0], t01 = base[1], t02 = base[2];
    const float t10 = base[3], t11 = base[4], t12 = base[5];
    const float* __restrict__ img = base + 6;
    float* __restrict__ outb = out + (long long)b * IMG_ELEMS;

    const int tid = threadIdx.x;

    if (fabsf(t10) <= fabsf(t11)) {
        // ---- Case A: lanes along w (y-step per lane = t10 = min). ----
        // Tile: 8 rows x 256 cols. Stores directly coalesced.
        const int h0 = beta * 8;
        const int w  = tid;
        #pragma unroll
        for (int r = 0; r < 8; ++r) {
            float o[3];
            sample_px(img, t00, t01, t02, t10, t11, t12, w, h0 + r, o);
            F3 s; s.v[0] = o[0]; s.v[1] = o[1]; s.v[2] = o[2];
            *reinterpret_cast<F3*>(outb + ((h0 + r) * WW + w) * CC) = s;
        }
    } else {
        // ---- Case B: lanes along h (y-step per lane = t11 = min). ----
        // Tile: 64 rows x 32 cols; results staged in LDS, stored coalesced.
        const int h0 = (beta & 3) * 64;
        const int w0 = (beta >> 2) * 32;
        const int l  = tid & 63;          // lane -> h offset
        const int v  = tid >> 6;          // wave -> col group
        #pragma unroll
        for (int j = 0; j < 8; ++j) {
            const int c = v * 8 + j;      // col 0..31
            float o[3];
            sample_px(img, t00, t01, t02, t10, t11, t12, w0 + c, h0 + l, o);
            float* dst = &lds[l * LDSW + c * 3];
            dst[0] = o[0]; dst[1] = o[1]; dst[2] = o[2];
        }
        __syncthreads();
        // Store phase: tile row r = 32 px = 96 dwords = 48 dword-pairs.
        #pragma unroll
        for (int p = 0; p < 12; ++p) {
            const int d2 = p * 256 + tid;     // pair index 0..3071
            const int r  = d2 / 48;
            const int k  = d2 % 48;
            const f32x2 val = *reinterpret_cast<const f32x2*>(&lds[r * LDSW + k * 2]);
            *reinterpret_cast<f32x2*>(outb + (h0 + r) * (WW * CC) + w0 * CC + k * 2) = val;
        }
    }
}

extern "C" void kernel_launch(void* const* d_in, const int* in_sizes, int n_in,
                              void* d_out, int out_size, void* d_ws, size_t ws_size,
                              hipStream_t stream)
{
    const float* in = (const float*)d_in[0];
    float* out = (float*)d_out;
    dim3 grid(NWG), block(256);
    bilinear_sampler_kernel<<<grid, block, 0, stream>>>(in, out);
}